// Round 1
// baseline (2277.004 us; speedup 1.0000x reference)
//
#include <hip/hip_runtime.h>
#include <cstdint>
#include <cstddef>

#define NN 50000
#define EE 800000
#define EPQ (EE + NN)
#define NEG_SLOPE 0.2f
#define BN_EPS 1e-5f

static __device__ __forceinline__ float lrelu(float x) { return x > 0.f ? x : x * NEG_SLOPE; }

// ---------------- CSR build ----------------
__global__ void init_count(int* __restrict__ count) {
    int i = blockIdx.x * blockDim.x + threadIdx.x;
    if (i < NN) count[i] = 1;  // self loop contributes 1 to each node
}

__global__ void hist_kernel(const int* __restrict__ dst, int* __restrict__ count) {
    int e = blockIdx.x * blockDim.x + threadIdx.x;
    if (e < EE) atomicAdd(&count[dst[e]], 1);
}

__global__ void scan_kernel(const int* __restrict__ count, int* __restrict__ rowptr,
                            int* __restrict__ cursor) {
    __shared__ int sums[1024];
    int tid = threadIdx.x;
    const int CH = (NN + 1023) / 1024;  // 49
    int base = tid * CH;
    int s = 0;
    for (int j = 0; j < CH; j++) {
        int idx = base + j;
        if (idx < NN) s += count[idx];
    }
    sums[tid] = s;
    __syncthreads();
    for (int off = 1; off < 1024; off <<= 1) {
        int v = (tid >= off) ? sums[tid - off] : 0;
        __syncthreads();
        sums[tid] += v;
        __syncthreads();
    }
    int run = (tid == 0) ? 0 : sums[tid - 1];
    for (int j = 0; j < CH; j++) {
        int idx = base + j;
        if (idx < NN) {
            rowptr[idx] = run;
            cursor[idx] = run;
            run += count[idx];
        }
    }
    if (tid == 1023) rowptr[NN] = sums[1023];
}

__global__ void scatter_kernel(const int* __restrict__ src, const int* __restrict__ dst,
                               int* __restrict__ cursor, int* __restrict__ csr) {
    int e = blockIdx.x * blockDim.x + threadIdx.x;
    if (e < EE) {
        int d = dst[e];
        int slot = atomicAdd(&cursor[d], 1);
        csr[slot] = src[e];
    } else if (e < EPQ) {
        int i = e - EE;
        int slot = atomicAdd(&cursor[i], 1);
        csr[slot] = i;
    }
}

// ---------------- f32 tiled GEMM: C[M,N] = A[M,K] @ B[K,N] ----------------
__global__ __launch_bounds__(256) void gemm_f32(const float* __restrict__ A,
                                                const float* __restrict__ B,
                                                float* __restrict__ C, int M, int N, int K) {
    __shared__ float As[16][65];
    __shared__ float Bs[16][64];
    int t = threadIdx.x;
    int bm = blockIdx.x * 64, bn = blockIdx.y * 64;
    int tx = t & 15, ty = t >> 4;
    float acc[4][4] = {};
    int arow = t >> 2;          // 0..63
    int acol4 = (t & 3) * 4;    // 0,4,8,12
    int brow = t >> 4;          // 0..15
    int bcol4 = (t & 15) * 4;   // 0..60
    for (int k0 = 0; k0 < K; k0 += 16) {
        float4 av = {0.f, 0.f, 0.f, 0.f};
        if (bm + arow < M) av = *(const float4*)(A + (size_t)(bm + arow) * K + k0 + acol4);
        As[acol4 + 0][arow] = av.x;
        As[acol4 + 1][arow] = av.y;
        As[acol4 + 2][arow] = av.z;
        As[acol4 + 3][arow] = av.w;
        float4 bv = {0.f, 0.f, 0.f, 0.f};
        if (bn + bcol4 < N) bv = *(const float4*)(B + (size_t)(k0 + brow) * N + bn + bcol4);
        *(float4*)&Bs[brow][bcol4] = bv;
        __syncthreads();
#pragma unroll
        for (int k = 0; k < 16; k++) {
            float a[4], b[4];
#pragma unroll
            for (int i = 0; i < 4; i++) a[i] = As[k][ty * 4 + i];
#pragma unroll
            for (int j = 0; j < 4; j++) b[j] = Bs[k][tx * 4 + j];
#pragma unroll
            for (int i = 0; i < 4; i++)
#pragma unroll
                for (int j = 0; j < 4; j++) acc[i][j] += a[i] * b[j];
        }
        __syncthreads();
    }
#pragma unroll
    for (int i = 0; i < 4; i++) {
        int m = bm + ty * 4 + i;
        if (m < M) {
#pragma unroll
            for (int j = 0; j < 4; j++) {
                int n = bn + tx * 4 + j;
                if (n < N) C[(size_t)m * N + n] = acc[i][j];
            }
        }
    }
}

// ---------------- attention coefficients (layers 0/1: H=4, C=128) ----------------
__global__ void alpha01(const float* __restrict__ h, const float* __restrict__ aws,
                        const float* __restrict__ awd, float* __restrict__ asn,
                        float* __restrict__ adn) {
    int wave = threadIdx.x >> 6, lane = threadIdx.x & 63;
    int i = blockIdx.x * 4 + wave;
    if (i >= NN) return;
    const float* row = h + (size_t)i * 512;
#pragma unroll
    for (int hh = 0; hh < 4; hh++) {
        float s = row[hh * 128 + lane] * aws[hh * 128 + lane] +
                  row[hh * 128 + 64 + lane] * aws[hh * 128 + 64 + lane];
        float d = row[hh * 128 + lane] * awd[hh * 128 + lane] +
                  row[hh * 128 + 64 + lane] * awd[hh * 128 + 64 + lane];
#pragma unroll
        for (int off = 32; off; off >>= 1) {
            s += __shfl_xor(s, off);
            d += __shfl_xor(d, off);
        }
        if (lane == 0) {
            asn[i * 4 + hh] = s;
            adn[i * 4 + hh] = d;
        }
    }
}

// ---------------- softmax + aggregation + bias + BN + ELU (layers 0/1) ----------------
__global__ __launch_bounds__(512) void agg01(const float* __restrict__ h,
                                             const float* __restrict__ asv,
                                             const float* __restrict__ adv,
                                             const int* __restrict__ rowptr,
                                             const int* __restrict__ csr,
                                             const float* __restrict__ bias,
                                             const float* __restrict__ g,
                                             const float* __restrict__ bt,
                                             const float* __restrict__ mean,
                                             const float* __restrict__ var,
                                             float* __restrict__ out) {
    int i = blockIdx.x;
    int t = threadIdx.x;
    int lane = t & 63;
    int head = t >> 7;
    int start = rowptr[i], end = rowptr[i + 1];
    float adst = adv[i * 4 + head];
    // pass 1: max (lane-parallel)
    float m = -INFINITY;
    for (int e = start + lane; e < end; e += 64) {
        float s = lrelu(asv[csr[e] * 4 + head] + adst);
        m = fmaxf(m, s);
    }
#pragma unroll
    for (int off = 32; off; off >>= 1) m = fmaxf(m, __shfl_xor(m, off));
    // pass 2: denom
    float denom = 0.f;
    for (int e = start + lane; e < end; e += 64) {
        float s = lrelu(asv[csr[e] * 4 + head] + adst);
        denom += __expf(s - m);
    }
#pragma unroll
    for (int off = 32; off; off >>= 1) denom += __shfl_xor(denom, off);
    // pass 3: weighted row accumulation
    float acc = 0.f;
    int c = t & 127;
    for (int e = start; e < end; e++) {
        int src = csr[e];  // broadcast
        float s = lrelu(asv[src * 4 + head] + adst);
        float wgt = __expf(s - m);
        acc += wgt * h[(size_t)src * 512 + head * 128 + c];
    }
    float val = acc / (denom + 1e-16f) + bias[t];
    float sc = g[t] * rsqrtf(var[t] + BN_EPS);
    val = (val - mean[t]) * sc + bt[t];
    val = val > 0.f ? val : expm1f(val);
    out[(size_t)i * 512 + t] = val;
}

// ---------------- layer 2: H=6, C=40 ----------------
__global__ void alpha2(const float* __restrict__ h, const float* __restrict__ aws,
                       const float* __restrict__ awd, float* __restrict__ asn,
                       float* __restrict__ adn) {
    int wave = threadIdx.x >> 6, lane = threadIdx.x & 63;
    int i = blockIdx.x * 4 + wave;
    if (i >= NN) return;
    const float* row = h + (size_t)i * 240;
#pragma unroll
    for (int hh = 0; hh < 6; hh++) {
        float s = 0.f, d = 0.f;
        if (lane < 40) {
            s = row[hh * 40 + lane] * aws[hh * 40 + lane];
            d = row[hh * 40 + lane] * awd[hh * 40 + lane];
        }
#pragma unroll
        for (int off = 32; off; off >>= 1) {
            s += __shfl_xor(s, off);
            d += __shfl_xor(d, off);
        }
        if (lane == 0) {
            asn[i * 6 + hh] = s;
            adn[i * 6 + hh] = d;
        }
    }
}

__global__ __launch_bounds__(256) void agg2(const float* __restrict__ h,
                                            const float* __restrict__ asv,
                                            const float* __restrict__ adv,
                                            const int* __restrict__ rowptr,
                                            const int* __restrict__ csr,
                                            float* __restrict__ out) {
    __shared__ float sm[6], sden[6];
    int i = blockIdx.x;
    int t = threadIdx.x;
    int start = rowptr[i], end = rowptr[i + 1];
    int lane = t & 63;
    if (t < 64) {
        for (int hh = 0; hh < 6; hh++) {
            float adst = adv[i * 6 + hh];
            float m = -INFINITY;
            for (int e = start + lane; e < end; e += 64) {
                float s = lrelu(asv[csr[e] * 6 + hh] + adst);
                m = fmaxf(m, s);
            }
#pragma unroll
            for (int off = 32; off; off >>= 1) m = fmaxf(m, __shfl_xor(m, off));
            float den = 0.f;
            for (int e = start + lane; e < end; e += 64) {
                float s = lrelu(asv[csr[e] * 6 + hh] + adst);
                den += __expf(s - m);
            }
#pragma unroll
            for (int off = 32; off; off >>= 1) den += __shfl_xor(den, off);
            if (lane == 0) {
                sm[hh] = m;
                sden[hh] = den;
            }
        }
    }
    __syncthreads();
    if (t < 240) {
        int head = t / 40;
        float adst = adv[i * 6 + head];
        float m = sm[head], den = sden[head];
        float acc = 0.f;
        for (int e = start; e < end; e++) {
            int src = csr[e];
            float s = lrelu(asv[src * 6 + head] + adst);
            acc += __expf(s - m) * h[(size_t)src * 240 + t];
        }
        out[(size_t)i * 240 + t] = acc / (den + 1e-16f);
    }
}

__global__ void finalk(const float* __restrict__ agg, const float* __restrict__ b2,
                       float* __restrict__ out) {
    int wave = threadIdx.x >> 6, lane = threadIdx.x & 63;
    int i = blockIdx.x * 4 + wave;
    if (i >= NN) return;
    float v = 0.f;
    if (lane < 40) {
#pragma unroll
        for (int hh = 0; hh < 6; hh++) v += agg[(size_t)i * 240 + hh * 40 + lane];
        v = v * (1.0f / 6.0f) + b2[lane];
    }
    float m = lane < 40 ? v : -INFINITY;
#pragma unroll
    for (int off = 32; off; off >>= 1) m = fmaxf(m, __shfl_xor(m, off));
    float s = lane < 40 ? __expf(v - m) : 0.f;
#pragma unroll
    for (int off = 32; off; off >>= 1) s += __shfl_xor(s, off);
    if (lane < 40) out[(size_t)i * 40 + lane] = v - m - logf(s);
}

extern "C" void kernel_launch(void* const* d_in, const int* in_sizes, int n_in,
                              void* d_out, int out_size, void* d_ws, size_t ws_size,
                              hipStream_t stream) {
    const float* x   = (const float*)d_in[0];
    const int*   ei  = (const int*)d_in[1];
    const float* W0  = (const float*)d_in[2];
    const float* as0 = (const float*)d_in[3];
    const float* ad0 = (const float*)d_in[4];
    const float* b0  = (const float*)d_in[5];
    const float* g0  = (const float*)d_in[6];
    const float* bt0 = (const float*)d_in[7];
    const float* m0  = (const float*)d_in[8];
    const float* v0  = (const float*)d_in[9];
    const float* W1  = (const float*)d_in[10];
    const float* as1 = (const float*)d_in[11];
    const float* ad1 = (const float*)d_in[12];
    const float* b1  = (const float*)d_in[13];
    const float* g1  = (const float*)d_in[14];
    const float* bt1 = (const float*)d_in[15];
    const float* m1  = (const float*)d_in[16];
    const float* v1  = (const float*)d_in[17];
    const float* W2  = (const float*)d_in[18];
    const float* as2w = (const float*)d_in[19];
    const float* ad2w = (const float*)d_in[20];
    const float* b2  = (const float*)d_in[21];
    float* out = (float*)d_out;
    const int* srcv = ei;
    const int* dstv = ei + EE;

    char* w = (char*)d_ws;
    float* bufA = (float*)w; w += (size_t)NN * 512 * sizeof(float);
    float* bufB = (float*)w; w += (size_t)NN * 512 * sizeof(float);
    float* asn  = (float*)w; w += (size_t)NN * 6 * sizeof(float);
    float* adn  = (float*)w; w += (size_t)NN * 6 * sizeof(float);
    int* count  = (int*)w;   w += (size_t)(NN + 8) * sizeof(int);
    int* rowptr = (int*)w;   w += (size_t)(NN + 8) * sizeof(int);
    int* cursor = (int*)w;   w += (size_t)(NN + 8) * sizeof(int);
    int* csr    = (int*)w;   w += (size_t)EPQ * sizeof(int);

    // CSR build (by dst), deterministic work each call
    init_count<<<(NN + 255) / 256, 256, 0, stream>>>(count);
    hist_kernel<<<(EE + 255) / 256, 256, 0, stream>>>(dstv, count);
    scan_kernel<<<1, 1024, 0, stream>>>(count, rowptr, cursor);
    scatter_kernel<<<(EPQ + 255) / 256, 256, 0, stream>>>(srcv, dstv, cursor, csr);

    // Layer 0: GATConv(128 -> 4x128, concat) + bias + BN + ELU
    gemm_f32<<<dim3(782, 8), 256, 0, stream>>>(x, W0, bufA, NN, 512, 128);
    alpha01<<<(NN + 3) / 4, 256, 0, stream>>>(bufA, as0, ad0, asn, adn);
    agg01<<<NN, 512, 0, stream>>>(bufA, asn, adn, rowptr, csr, b0, g0, bt0, m0, v0, bufB);

    // Layer 1: GATConv(512 -> 4x128, concat) + bias + BN + ELU
    gemm_f32<<<dim3(782, 8), 256, 0, stream>>>(bufB, W1, bufA, NN, 512, 512);
    alpha01<<<(NN + 3) / 4, 256, 0, stream>>>(bufA, as1, ad1, asn, adn);
    agg01<<<NN, 512, 0, stream>>>(bufA, asn, adn, rowptr, csr, b1, g1, bt1, m1, v1, bufB);

    // Layer 2: GATConv(512 -> 6x40, mean) + bias + log_softmax
    gemm_f32<<<dim3(782, 4), 256, 0, stream>>>(bufB, W2, bufA, NN, 240, 512);
    alpha2<<<(NN + 3) / 4, 256, 0, stream>>>(bufA, as2w, ad2w, asn, adn);
    agg2<<<NN, 256, 0, stream>>>(bufA, asn, adn, rowptr, csr, bufB);
    finalk<<<(NN + 3) / 4, 256, 0, stream>>>(bufB, b2, out);
}

// Round 2
// 976.104 us; speedup vs baseline: 2.3327x; 2.3327x over previous
//
#include <hip/hip_runtime.h>
#include <cstdint>
#include <cstddef>

#define NN 50000
#define EE 800000
#define EPQ (EE + NN)
#define NEG_SLOPE 0.2f
#define BN_EPS 1e-5f

typedef _Float16 f16x8 __attribute__((ext_vector_type(8)));
typedef _Float16 f16x4 __attribute__((ext_vector_type(4)));
typedef _Float16 f16x2 __attribute__((ext_vector_type(2)));
typedef float f32x4 __attribute__((ext_vector_type(4)));

static __device__ __forceinline__ float lrelu(float x) { return x > 0.f ? x : x * NEG_SLOPE; }

// ---------------- CSR build ----------------
__global__ void init_count(int* __restrict__ count) {
    int i = blockIdx.x * blockDim.x + threadIdx.x;
    if (i < NN) count[i] = 1;  // self loop
}

__global__ void hist_kernel(const int* __restrict__ dst, int* __restrict__ count) {
    int e = blockIdx.x * blockDim.x + threadIdx.x;
    if (e < EE) atomicAdd(&count[dst[e]], 1);
}

__global__ void scan_kernel(const int* __restrict__ count, int* __restrict__ rowptr,
                            int* __restrict__ cursor) {
    __shared__ int sums[1024];
    int tid = threadIdx.x;
    const int CH = (NN + 1023) / 1024;
    int base = tid * CH;
    int s = 0;
    for (int j = 0; j < CH; j++) {
        int idx = base + j;
        if (idx < NN) s += count[idx];
    }
    sums[tid] = s;
    __syncthreads();
    for (int off = 1; off < 1024; off <<= 1) {
        int v = (tid >= off) ? sums[tid - off] : 0;
        __syncthreads();
        sums[tid] += v;
        __syncthreads();
    }
    int run = (tid == 0) ? 0 : sums[tid - 1];
    for (int j = 0; j < CH; j++) {
        int idx = base + j;
        if (idx < NN) {
            rowptr[idx] = run;
            cursor[idx] = run;
            run += count[idx];
        }
    }
    if (tid == 1023) rowptr[NN] = sums[1023];
}

__global__ void scatter_kernel(const int* __restrict__ src, const int* __restrict__ dst,
                               int* __restrict__ cursor, int* __restrict__ csrs,
                               int* __restrict__ csrd) {
    int e = blockIdx.x * blockDim.x + threadIdx.x;
    if (e < EE) {
        int d = dst[e];
        int slot = atomicAdd(&cursor[d], 1);
        csrs[slot] = src[e];
        csrd[slot] = d;
    } else if (e < EPQ) {
        int i = e - EE;
        int slot = atomicAdd(&cursor[i], 1);
        csrs[slot] = i;
        csrd[slot] = i;
    }
}

// ---------------- casts ----------------
__global__ void cast_x_kernel(const float* __restrict__ in, _Float16* __restrict__ out, int n4) {
    int i = blockIdx.x * blockDim.x + threadIdx.x;
    if (i >= n4) return;
    f32x4 v = *(const f32x4*)(in + (size_t)i * 4);
    f16x4 o;
    o[0] = (_Float16)v[0]; o[1] = (_Float16)v[1]; o[2] = (_Float16)v[2]; o[3] = (_Float16)v[3];
    *(f16x4*)(out + (size_t)i * 4) = o;
}

// W [K][Nc] f32 -> Wt [Nc][K] f16
__global__ __launch_bounds__(256) void tcast_kernel(const float* __restrict__ W,
                                                    _Float16* __restrict__ Wt, int K, int Nc) {
    __shared__ float tile[32][33];
    int bx = blockIdx.x * 32;  // Nc
    int by = blockIdx.y * 32;  // K
    int tx = threadIdx.x & 31, ty = threadIdx.x >> 5;
#pragma unroll
    for (int r = 0; r < 32; r += 8) {
        int k = by + ty + r, n = bx + tx;
        tile[ty + r][tx] = (k < K && n < Nc) ? W[(size_t)k * Nc + n] : 0.f;
    }
    __syncthreads();
#pragma unroll
    for (int r = 0; r < 32; r += 8) {
        int n = bx + ty + r, k = by + tx;
        if (n < Nc && k < K) Wt[(size_t)n * K + k] = (_Float16)tile[tx][ty + r];
    }
}

// ---------------- f16 MFMA GEMM: C[M,Nc] = A[M,K] @ Bt[Nc,K]^T ----------------
__global__ __launch_bounds__(256) void gemm_f16(const _Float16* __restrict__ A,
                                                const _Float16* __restrict__ Bt,
                                                _Float16* __restrict__ C, int M, int Nc, int K) {
    __shared__ __align__(16) _Float16 As[128 * 64];
    __shared__ __align__(16) _Float16 Bs[128 * 64];
    const int t = threadIdx.x;
    const int bm = blockIdx.x * 128;
    const int bn = blockIdx.y * 128;
    const int wid = t >> 6, lane = t & 63;
    const int wm = (wid >> 1) * 64, wn = (wid & 1) * 64;
    f32x4 acc[4][4] = {};
    const int srow = t >> 3;  // 0..31
    const int sc8 = t & 7;    // 16B chunk within 64-col row
    for (int k0 = 0; k0 < K; k0 += 64) {
        __syncthreads();
#pragma unroll
        for (int it = 0; it < 4; ++it) {
            int row = it * 32 + srow;
            int c8s = sc8 ^ (row & 7);
            uint4 va = make_uint4(0, 0, 0, 0);
            int gr = bm + row;
            if (gr < M) va = *(const uint4*)(A + (size_t)gr * K + k0 + sc8 * 8);
            *(uint4*)((char*)As + row * 128 + c8s * 16) = va;
            uint4 vb = make_uint4(0, 0, 0, 0);
            int nr = bn + row;
            if (nr < Nc) vb = *(const uint4*)(Bt + (size_t)nr * K + k0 + sc8 * 8);
            *(uint4*)((char*)Bs + row * 128 + c8s * 16) = vb;
        }
        __syncthreads();
#pragma unroll
        for (int ks = 0; ks < 2; ++ks) {
            f16x8 af[4], bf[4];
#pragma unroll
            for (int mi = 0; mi < 4; ++mi) {
                int row = wm + mi * 16 + (lane & 15);
                int c8 = (ks * 4 + (lane >> 4)) ^ (row & 7);
                af[mi] = *(const f16x8*)((const char*)As + row * 128 + c8 * 16);
            }
#pragma unroll
            for (int ni = 0; ni < 4; ++ni) {
                int row = wn + ni * 16 + (lane & 15);
                int c8 = (ks * 4 + (lane >> 4)) ^ (row & 7);
                bf[ni] = *(const f16x8*)((const char*)Bs + row * 128 + c8 * 16);
            }
#pragma unroll
            for (int mi = 0; mi < 4; ++mi)
#pragma unroll
                for (int ni = 0; ni < 4; ++ni)
                    acc[mi][ni] = __builtin_amdgcn_mfma_f32_16x16x32_f16(af[mi], bf[ni],
                                                                         acc[mi][ni], 0, 0, 0);
        }
    }
#pragma unroll
    for (int mi = 0; mi < 4; ++mi) {
#pragma unroll
        for (int r = 0; r < 4; ++r) {
            int grow = bm + wm + mi * 16 + (lane >> 4) * 4 + r;
            if (grow < M) {
#pragma unroll
                for (int ni = 0; ni < 4; ++ni) {
                    int gcol = bn + wn + ni * 16 + (lane & 15);
                    if (gcol < Nc) C[(size_t)grow * Nc + gcol] = (_Float16)acc[mi][ni][r];
                }
            }
        }
    }
}

// ---------------- alpha (layers 0/1): one wave per node ----------------
__global__ __launch_bounds__(256) void alpha01(const _Float16* __restrict__ h,
                                               const float* __restrict__ aws,
                                               const float* __restrict__ awd,
                                               float* __restrict__ asn, float* __restrict__ adn) {
    int wid = threadIdx.x >> 6, lane = threadIdx.x & 63;
    int i = blockIdx.x * 4 + wid;
    if (i >= NN) return;
    f16x8 v = *(const f16x8*)(h + (size_t)i * 512 + lane * 8);
    float s = 0.f, d = 0.f;
#pragma unroll
    for (int j = 0; j < 8; j++) {
        float f = (float)v[j];
        s += f * aws[lane * 8 + j];
        d += f * awd[lane * 8 + j];
    }
#pragma unroll
    for (int off = 1; off < 16; off <<= 1) {
        s += __shfl_xor(s, off);
        d += __shfl_xor(d, off);
    }
    if ((lane & 15) == 0) {
        int hh = lane >> 4;
        asn[i * 4 + hh] = s;
        adn[i * 4 + hh] = d;
    }
}

// ---------------- per-edge scores (layers 0/1) ----------------
__global__ void edge_score01(const int* __restrict__ csrs, const int* __restrict__ csrd,
                             const float* __restrict__ asn, const float* __restrict__ adn,
                             float* __restrict__ sc) {
    int e = blockIdx.x * blockDim.x + threadIdx.x;
    if (e >= EPQ) return;
    int s = csrs[e], d = csrd[e];
    f32x4 a = *(const f32x4*)(asn + (size_t)s * 4);
    f32x4 b = *(const f32x4*)(adn + (size_t)d * 4);
#pragma unroll
    for (int j = 0; j < 4; j++) a[j] = lrelu(a[j] + b[j]);
    *(f32x4*)(sc + (size_t)e * 4) = a;
}

// ---------------- per-node softmax (layers 0/1): exp in place + 1/denom ----------------
__global__ __launch_bounds__(256) void node_softmax01(const int* __restrict__ rowptr,
                                                      float* __restrict__ sc,
                                                      float* __restrict__ rden) {
    int wid = threadIdx.x >> 6, lane = threadIdx.x & 63;
    int i = blockIdx.x * 4 + wid;
    if (i >= NN) return;
    int start = rowptr[i], end = rowptr[i + 1];
    f32x4 m = {-1e30f, -1e30f, -1e30f, -1e30f};
    for (int e = start + lane; e < end; e += 64) {
        f32x4 s = *(const f32x4*)(sc + (size_t)e * 4);
#pragma unroll
        for (int j = 0; j < 4; j++) m[j] = fmaxf(m[j], s[j]);
    }
#pragma unroll
    for (int off = 32; off; off >>= 1) {
#pragma unroll
        for (int j = 0; j < 4; j++) m[j] = fmaxf(m[j], __shfl_xor(m[j], off));
    }
    f32x4 den = {0.f, 0.f, 0.f, 0.f};
    for (int e = start + lane; e < end; e += 64) {
        f32x4 s = *(const f32x4*)(sc + (size_t)e * 4);
#pragma unroll
        for (int j = 0; j < 4; j++) s[j] = __expf(s[j] - m[j]);
        *(f32x4*)(sc + (size_t)e * 4) = s;
        den += s;
    }
#pragma unroll
    for (int off = 32; off; off >>= 1) {
#pragma unroll
        for (int j = 0; j < 4; j++) den[j] += __shfl_xor(den[j], off);
    }
    if (lane == 0) {
        f32x4 r;
#pragma unroll
        for (int j = 0; j < 4; j++) r[j] = 1.f / (den[j] + 1e-16f);
        *(f32x4*)(rden + (size_t)i * 4) = r;
    }
}

// ---------------- aggregation + bias + BN + ELU (layers 0/1) ----------------
__global__ __launch_bounds__(256) void agg01(const _Float16* __restrict__ h,
                                             const float* __restrict__ wb,
                                             const float* __restrict__ rden,
                                             const int* __restrict__ rowptr,
                                             const int* __restrict__ csr,
                                             const float* __restrict__ bias,
                                             const float* __restrict__ g,
                                             const float* __restrict__ bt,
                                             const float* __restrict__ mean,
                                             const float* __restrict__ var,
                                             _Float16* __restrict__ out) {
    int i = blockIdx.x;
    int t = threadIdx.x;
    int head = t >> 6;
    int ch = head * 128 + (t & 63) * 2;
    int start = rowptr[i], end = rowptr[i + 1];
    float a0 = 0.f, a1 = 0.f;
    int e = start;
    for (; e + 2 <= end; e += 2) {
        int s0 = csr[e], s1 = csr[e + 1];
        float w0 = wb[(size_t)e * 4 + head], w1 = wb[(size_t)(e + 1) * 4 + head];
        f16x2 p0 = *(const f16x2*)(h + (size_t)s0 * 512 + ch);
        f16x2 p1 = *(const f16x2*)(h + (size_t)s1 * 512 + ch);
        a0 += w0 * (float)p0[0] + w1 * (float)p1[0];
        a1 += w0 * (float)p0[1] + w1 * (float)p1[1];
    }
    if (e < end) {
        int s0 = csr[e];
        float w0 = wb[(size_t)e * 4 + head];
        f16x2 p0 = *(const f16x2*)(h + (size_t)s0 * 512 + ch);
        a0 += w0 * (float)p0[0];
        a1 += w0 * (float)p0[1];
    }
    float r = rden[i * 4 + head];
    float v0 = a0 * r + bias[ch], v1 = a1 * r + bias[ch + 1];
    v0 = (v0 - mean[ch]) * (g[ch] * rsqrtf(var[ch] + BN_EPS)) + bt[ch];
    v1 = (v1 - mean[ch + 1]) * (g[ch + 1] * rsqrtf(var[ch + 1] + BN_EPS)) + bt[ch + 1];
    v0 = v0 > 0.f ? v0 : expm1f(v0);
    v1 = v1 > 0.f ? v1 : expm1f(v1);
    f16x2 o;
    o[0] = (_Float16)v0;
    o[1] = (_Float16)v1;
    *(f16x2*)(out + (size_t)i * 512 + ch) = o;
}

// ---------------- layer 2 ----------------
__global__ __launch_bounds__(256) void alpha2k(const _Float16* __restrict__ h2,
                                               const float* __restrict__ aws,
                                               const float* __restrict__ awd,
                                               float* __restrict__ asn, float* __restrict__ adn) {
    int wid = threadIdx.x >> 6, lane = threadIdx.x & 63;
    int i = blockIdx.x * 4 + wid;
    if (i >= NN) return;
    const _Float16* row = h2 + (size_t)i * 240;
#pragma unroll
    for (int hh = 0; hh < 6; hh++) {
        float s = 0.f, d = 0.f;
        if (lane < 40) {
            float f = (float)row[hh * 40 + lane];
            s = f * aws[hh * 40 + lane];
            d = f * awd[hh * 40 + lane];
        }
#pragma unroll
        for (int off = 32; off; off >>= 1) {
            s += __shfl_xor(s, off);
            d += __shfl_xor(d, off);
        }
        if (lane == 0) {
            asn[i * 6 + hh] = s;
            adn[i * 6 + hh] = d;
        }
    }
}

__global__ void edge_score2(const int* __restrict__ csrs, const int* __restrict__ csrd,
                            const float* __restrict__ asn, const float* __restrict__ adn,
                            float* __restrict__ sc2) {
    int e = blockIdx.x * blockDim.x + threadIdx.x;
    if (e >= EPQ) return;
    int s = csrs[e], d = csrd[e];
#pragma unroll
    for (int hh = 0; hh < 6; hh++)
        sc2[(size_t)hh * EPQ + e] = lrelu(asn[s * 6 + hh] + adn[d * 6 + hh]);
}

__global__ __launch_bounds__(256) void node_softmax2(const int* __restrict__ rowptr,
                                                     float* __restrict__ sc2,
                                                     float* __restrict__ rden2) {
    int wid = threadIdx.x >> 6, lane = threadIdx.x & 63;
    int i = blockIdx.x * 4 + wid;
    if (i >= NN) return;
    int start = rowptr[i], end = rowptr[i + 1];
    for (int hh = 0; hh < 6; hh++) {
        float* p = sc2 + (size_t)hh * EPQ;
        float m = -1e30f;
        for (int e = start + lane; e < end; e += 64) m = fmaxf(m, p[e]);
#pragma unroll
        for (int off = 32; off; off >>= 1) m = fmaxf(m, __shfl_xor(m, off));
        float den = 0.f;
        for (int e = start + lane; e < end; e += 64) {
            float w = __expf(p[e] - m);
            p[e] = w;
            den += w;
        }
#pragma unroll
        for (int off = 32; off; off >>= 1) den += __shfl_xor(den, off);
        if (lane == 0) rden2[i * 6 + hh] = 1.f / (den + 1e-16f);
    }
}

__global__ __launch_bounds__(128) void agg2(const _Float16* __restrict__ h2,
                                            const float* __restrict__ wb2,
                                            const float* __restrict__ rden2,
                                            const int* __restrict__ rowptr,
                                            const int* __restrict__ csr,
                                            float* __restrict__ aggF) {
    int i = blockIdx.x;
    int t = threadIdx.x;
    if (t >= 120) return;
    int ch = t * 2;
    int head = t / 20;
    int start = rowptr[i], end = rowptr[i + 1];
    const float* wp = wb2 + (size_t)head * EPQ;
    float a0 = 0.f, a1 = 0.f;
    int e = start;
    for (; e + 2 <= end; e += 2) {
        int s0 = csr[e], s1 = csr[e + 1];
        float w0 = wp[e], w1 = wp[e + 1];
        f16x2 p0 = *(const f16x2*)(h2 + (size_t)s0 * 240 + ch);
        f16x2 p1 = *(const f16x2*)(h2 + (size_t)s1 * 240 + ch);
        a0 += w0 * (float)p0[0] + w1 * (float)p1[0];
        a1 += w0 * (float)p0[1] + w1 * (float)p1[1];
    }
    if (e < end) {
        int s0 = csr[e];
        float w0 = wp[e];
        f16x2 p0 = *(const f16x2*)(h2 + (size_t)s0 * 240 + ch);
        a0 += w0 * (float)p0[0];
        a1 += w0 * (float)p0[1];
    }
    float r = rden2[i * 6 + head];
    aggF[(size_t)i * 240 + ch] = a0 * r;
    aggF[(size_t)i * 240 + ch + 1] = a1 * r;
}

__global__ void finalk(const float* __restrict__ agg, const float* __restrict__ b2,
                       float* __restrict__ out) {
    int wave = threadIdx.x >> 6, lane = threadIdx.x & 63;
    int i = blockIdx.x * 4 + wave;
    if (i >= NN) return;
    float v = 0.f;
    if (lane < 40) {
#pragma unroll
        for (int hh = 0; hh < 6; hh++) v += agg[(size_t)i * 240 + hh * 40 + lane];
        v = v * (1.0f / 6.0f) + b2[lane];
    }
    float m = lane < 40 ? v : -INFINITY;
#pragma unroll
    for (int off = 32; off; off >>= 1) m = fmaxf(m, __shfl_xor(m, off));
    float s = lane < 40 ? __expf(v - m) : 0.f;
#pragma unroll
    for (int off = 32; off; off >>= 1) s += __shfl_xor(s, off);
    if (lane < 40) out[(size_t)i * 40 + lane] = v - m - logf(s);
}

extern "C" void kernel_launch(void* const* d_in, const int* in_sizes, int n_in,
                              void* d_out, int out_size, void* d_ws, size_t ws_size,
                              hipStream_t stream) {
    const float* x   = (const float*)d_in[0];
    const int*   ei  = (const int*)d_in[1];
    const float* W0  = (const float*)d_in[2];
    const float* as0 = (const float*)d_in[3];
    const float* ad0 = (const float*)d_in[4];
    const float* b0  = (const float*)d_in[5];
    const float* g0  = (const float*)d_in[6];
    const float* bt0 = (const float*)d_in[7];
    const float* m0  = (const float*)d_in[8];
    const float* v0  = (const float*)d_in[9];
    const float* W1  = (const float*)d_in[10];
    const float* as1 = (const float*)d_in[11];
    const float* ad1 = (const float*)d_in[12];
    const float* b1  = (const float*)d_in[13];
    const float* g1  = (const float*)d_in[14];
    const float* bt1 = (const float*)d_in[15];
    const float* m1  = (const float*)d_in[16];
    const float* v1  = (const float*)d_in[17];
    const float* W2  = (const float*)d_in[18];
    const float* as2w = (const float*)d_in[19];
    const float* ad2w = (const float*)d_in[20];
    const float* b2  = (const float*)d_in[21];
    float* out = (float*)d_out;
    const int* srcv = ei;
    const int* dstv = ei + EE;

    char* w = (char*)d_ws;
    auto carve = [&](size_t bytes) {
        char* p = w;
        w += (bytes + 255) & ~(size_t)255;
        return p;
    };
    _Float16* xh   = (_Float16*)carve((size_t)NN * 128 * 2);
    _Float16* hA   = (_Float16*)carve((size_t)NN * 512 * 2);
    _Float16* actB = (_Float16*)carve((size_t)NN * 512 * 2);
    _Float16* W0t  = (_Float16*)carve((size_t)512 * 128 * 2);
    _Float16* W1t  = (_Float16*)carve((size_t)512 * 512 * 2);
    _Float16* W2t  = (_Float16*)carve((size_t)240 * 512 * 2);
    float* asn  = (float*)carve((size_t)NN * 6 * 4);
    float* adn  = (float*)carve((size_t)NN * 6 * 4);
    float* rden = (float*)carve((size_t)NN * 6 * 4);
    float* sc   = (float*)carve((size_t)EPQ * 6 * 4);
    int* count  = (int*)carve((size_t)(NN + 8) * 4);
    int* rowptr = (int*)carve((size_t)(NN + 8) * 4);
    int* cursor = (int*)carve((size_t)(NN + 8) * 4);
    int* csrs   = (int*)carve((size_t)EPQ * 4);
    int* csrd   = (int*)carve((size_t)EPQ * 4);
    _Float16* h2 = hA;              // reuse: L2 GEMM output [NN][240]
    float* aggF  = (float*)actB;    // reuse: layer-2 aggregate [NN][240] f32

    // CSR build
    init_count<<<(NN + 255) / 256, 256, 0, stream>>>(count);
    hist_kernel<<<(EE + 255) / 256, 256, 0, stream>>>(dstv, count);
    scan_kernel<<<1, 1024, 0, stream>>>(count, rowptr, cursor);
    scatter_kernel<<<(EPQ + 255) / 256, 256, 0, stream>>>(srcv, dstv, cursor, csrs, csrd);

    // casts
    cast_x_kernel<<<(NN * 128 / 4 + 255) / 256, 256, 0, stream>>>(x, xh, NN * 128 / 4);
    tcast_kernel<<<dim3(16, 4), 256, 0, stream>>>(W0, W0t, 128, 512);
    tcast_kernel<<<dim3(16, 16), 256, 0, stream>>>(W1, W1t, 512, 512);
    tcast_kernel<<<dim3(8, 16), 256, 0, stream>>>(W2, W2t, 512, 240);

    const int MT = (NN + 127) / 128;  // 391

    // Layer 0
    gemm_f16<<<dim3(MT, 4), 256, 0, stream>>>(xh, W0t, hA, NN, 512, 128);
    alpha01<<<(NN + 3) / 4, 256, 0, stream>>>(hA, as0, ad0, asn, adn);
    edge_score01<<<(EPQ + 255) / 256, 256, 0, stream>>>(csrs, csrd, asn, adn, sc);
    node_softmax01<<<(NN + 3) / 4, 256, 0, stream>>>(rowptr, sc, rden);
    agg01<<<NN, 256, 0, stream>>>(hA, sc, rden, rowptr, csrs, b0, g0, bt0, m0, v0, actB);

    // Layer 1
    gemm_f16<<<dim3(MT, 4), 256, 0, stream>>>(actB, W1t, hA, NN, 512, 512);
    alpha01<<<(NN + 3) / 4, 256, 0, stream>>>(hA, as1, ad1, asn, adn);
    edge_score01<<<(EPQ + 255) / 256, 256, 0, stream>>>(csrs, csrd, asn, adn, sc);
    node_softmax01<<<(NN + 3) / 4, 256, 0, stream>>>(rowptr, sc, rden);
    agg01<<<NN, 256, 0, stream>>>(hA, sc, rden, rowptr, csrs, b1, g1, bt1, m1, v1, actB);

    // Layer 2
    gemm_f16<<<dim3(MT, 2), 256, 0, stream>>>(actB, W2t, h2, NN, 240, 512);
    alpha2k<<<(NN + 3) / 4, 256, 0, stream>>>(h2, as2w, ad2w, asn, adn);
    edge_score2<<<(EPQ + 255) / 256, 256, 0, stream>>>(csrs, csrd, asn, adn, sc);
    node_softmax2<<<(NN + 3) / 4, 256, 0, stream>>>(rowptr, sc, rden);
    agg2<<<NN, 128, 0, stream>>>(h2, sc, rden, rowptr, csrs, aggF);
    finalk<<<(NN + 3) / 4, 256, 0, stream>>>(aggF, b2, out);
}

// Round 3
// 711.992 us; speedup vs baseline: 3.1981x; 1.3709x over previous
//
#include <hip/hip_runtime.h>
#include <cstdint>
#include <cstddef>

#define NN 50000
#define EE 800000
#define EPQ (EE + NN)
#define NEG_SLOPE 0.2f
#define BN_EPS 1e-5f
#define SCB 256
#define NBLK ((NN + SCB - 1) / SCB)

typedef _Float16 f16x8 __attribute__((ext_vector_type(8)));
typedef _Float16 f16x4 __attribute__((ext_vector_type(4)));
typedef _Float16 f16x2 __attribute__((ext_vector_type(2)));
typedef float f32x4 __attribute__((ext_vector_type(4)));
typedef unsigned int u32;

static __device__ __forceinline__ float lrelu(float x) { return x > 0.f ? x : x * NEG_SLOPE; }

// async global->LDS, 16B per lane; LDS dest = wave-uniform base + lane*16
static __device__ __forceinline__ void gld_lds16(const void* g, void* l) {
    __builtin_amdgcn_global_load_lds((const __attribute__((address_space(1))) u32*)g,
                                     (__attribute__((address_space(3))) u32*)l, 16, 0, 0);
}

// ---------------- CSR build ----------------
__global__ void init_count(int* __restrict__ count) {
    int i = blockIdx.x * blockDim.x + threadIdx.x;
    if (i < NN) count[i] = 1;  // self loop
}

__global__ void hist_kernel(const int* __restrict__ dst, int* __restrict__ count) {
    int e = blockIdx.x * blockDim.x + threadIdx.x;
    if (e < EE) atomicAdd(&count[dst[e]], 1);
}

__global__ __launch_bounds__(SCB) void scan1(const int* __restrict__ count,
                                             int* __restrict__ excl, int* __restrict__ bsum) {
    __shared__ int tmp[SCB];
    int b = blockIdx.x, t = threadIdx.x;
    int i = b * SCB + t;
    int v = (i < NN) ? count[i] : 0;
    tmp[t] = v;
    __syncthreads();
    for (int off = 1; off < SCB; off <<= 1) {
        int u = (t >= off) ? tmp[t - off] : 0;
        __syncthreads();
        tmp[t] += u;
        __syncthreads();
    }
    if (i < NN) excl[i] = tmp[t] - v;
    if (t == SCB - 1) bsum[b] = tmp[t];
}

__global__ __launch_bounds__(256) void scan2(const int* __restrict__ bsum, int* __restrict__ boff) {
    __shared__ int tmp[256];
    int t = threadIdx.x;
    int v = (t < NBLK) ? bsum[t] : 0;
    tmp[t] = v;
    __syncthreads();
    for (int off = 1; off < 256; off <<= 1) {
        int u = (t >= off) ? tmp[t - off] : 0;
        __syncthreads();
        tmp[t] += u;
        __syncthreads();
    }
    boff[t] = tmp[t] - v;
}

__global__ void scan3(const int* __restrict__ excl, const int* __restrict__ boff,
                      int* __restrict__ rowptr, int* __restrict__ cursor) {
    int i = blockIdx.x * blockDim.x + threadIdx.x;
    if (i < NN) {
        int r = excl[i] + boff[i / SCB];
        rowptr[i] = r;
        cursor[i] = r;
    }
    if (i == NN) rowptr[NN] = EPQ;
}

__global__ void scatter_kernel(const int* __restrict__ src, const int* __restrict__ dst,
                               int* __restrict__ cursor, int* __restrict__ csrs) {
    int e = blockIdx.x * blockDim.x + threadIdx.x;
    if (e < EE) {
        int d = dst[e];
        int slot = atomicAdd(&cursor[d], 1);
        csrs[slot] = src[e];
    } else if (e < EPQ) {
        int i = e - EE;
        int slot = atomicAdd(&cursor[i], 1);
        csrs[slot] = i;
    }
}

// ---------------- casts ----------------
__global__ void cast_x_kernel(const float* __restrict__ in, _Float16* __restrict__ out, int n4) {
    int i = blockIdx.x * blockDim.x + threadIdx.x;
    if (i >= n4) return;
    f32x4 v = *(const f32x4*)(in + (size_t)i * 4);
    f16x4 o;
    o[0] = (_Float16)v[0]; o[1] = (_Float16)v[1]; o[2] = (_Float16)v[2]; o[3] = (_Float16)v[3];
    *(f16x4*)(out + (size_t)i * 4) = o;
}

// W [K][Nc] f32 -> Wt [Nc][K] f16
__global__ __launch_bounds__(256) void tcast_kernel(const float* __restrict__ W,
                                                    _Float16* __restrict__ Wt, int K, int Nc) {
    __shared__ float tile[32][33];
    int bx = blockIdx.x * 32;
    int by = blockIdx.y * 32;
    int tx = threadIdx.x & 31, ty = threadIdx.x >> 5;
#pragma unroll
    for (int r = 0; r < 32; r += 8) {
        int k = by + ty + r, n = bx + tx;
        tile[ty + r][tx] = (k < K && n < Nc) ? W[(size_t)k * Nc + n] : 0.f;
    }
    __syncthreads();
#pragma unroll
    for (int r = 0; r < 32; r += 8) {
        int n = bx + ty + r, k = by + tx;
        if (n < Nc && k < K) Wt[(size_t)n * K + k] = (_Float16)tile[tx][ty + r];
    }
}

// ---------------- f16 MFMA GEMM: C[M,Nc] = A[M,K] @ Bt[Nc,K]^T ----------------
// Staging via global_load_lds (linear LDS dest); XOR swizzle applied on the
// GLOBAL source address (rule: both-sides-or-neither). OOB rows read garbage
// inside d_ws (harmless; discarded by C-store guard).
__global__ __launch_bounds__(256) void gemm_f16(const _Float16* __restrict__ A,
                                                const _Float16* __restrict__ Bt,
                                                _Float16* __restrict__ C, int M, int Nc, int K) {
    __shared__ __align__(16) _Float16 As[128 * 64];
    __shared__ __align__(16) _Float16 Bs[128 * 64];
    const int t = threadIdx.x;
    const int bm = blockIdx.x * 128;
    const int bn = blockIdx.y * 128;
    const int wid = t >> 6, lane = t & 63;
    const int wm = (wid >> 1) * 64, wn = (wid & 1) * 64;
    f32x4 acc[4][4] = {};
    for (int k0 = 0; k0 < K; k0 += 64) {
        __syncthreads();
#pragma unroll
        for (int it = 0; it < 4; ++it) {
            int rbase = it * 32 + wid * 8;          // wave-uniform
            int row = rbase + (lane >> 3);
            int c8g = (lane & 7) ^ (row & 7);       // pre-swizzled source chunk
            gld_lds16(A + (size_t)(bm + row) * K + k0 + c8g * 8, (char*)As + rbase * 128);
            gld_lds16(Bt + (size_t)(bn + row) * K + k0 + c8g * 8, (char*)Bs + rbase * 128);
        }
        __syncthreads();
#pragma unroll
        for (int ks = 0; ks < 2; ++ks) {
            f16x8 af[4], bf[4];
#pragma unroll
            for (int mi = 0; mi < 4; ++mi) {
                int row = wm + mi * 16 + (lane & 15);
                int c8 = (ks * 4 + (lane >> 4)) ^ (row & 7);
                af[mi] = *(const f16x8*)((const char*)As + row * 128 + c8 * 16);
            }
#pragma unroll
            for (int ni = 0; ni < 4; ++ni) {
                int row = wn + ni * 16 + (lane & 15);
                int c8 = (ks * 4 + (lane >> 4)) ^ (row & 7);
                bf[ni] = *(const f16x8*)((const char*)Bs + row * 128 + c8 * 16);
            }
#pragma unroll
            for (int mi = 0; mi < 4; ++mi)
#pragma unroll
                for (int ni = 0; ni < 4; ++ni)
                    acc[mi][ni] = __builtin_amdgcn_mfma_f32_16x16x32_f16(af[mi], bf[ni],
                                                                         acc[mi][ni], 0, 0, 0);
        }
    }
#pragma unroll
    for (int mi = 0; mi < 4; ++mi) {
#pragma unroll
        for (int r = 0; r < 4; ++r) {
            int grow = bm + wm + mi * 16 + (lane >> 4) * 4 + r;
            if (grow < M) {
#pragma unroll
                for (int ni = 0; ni < 4; ++ni) {
                    int gcol = bn + wn + ni * 16 + (lane & 15);
                    if (gcol < Nc) C[(size_t)grow * Nc + gcol] = (_Float16)acc[mi][ni][r];
                }
            }
        }
    }
}

// ---------------- alpha (layers 0/1): one wave per node ----------------
__global__ __launch_bounds__(256) void alpha01(const _Float16* __restrict__ h,
                                               const float* __restrict__ aws,
                                               const float* __restrict__ awd,
                                               float* __restrict__ asn, float* __restrict__ adn) {
    int wid = threadIdx.x >> 6, lane = threadIdx.x & 63;
    int i = blockIdx.x * 4 + wid;
    if (i >= NN) return;
    f16x8 v = *(const f16x8*)(h + (size_t)i * 512 + lane * 8);
    float s = 0.f, d = 0.f;
#pragma unroll
    for (int j = 0; j < 8; j++) {
        float f = (float)v[j];
        s += f * aws[lane * 8 + j];
        d += f * awd[lane * 8 + j];
    }
#pragma unroll
    for (int off = 1; off < 16; off <<= 1) {
        s += __shfl_xor(s, off);
        d += __shfl_xor(d, off);
    }
    if ((lane & 15) == 0) {
        int hh = lane >> 4;
        asn[i * 4 + hh] = s;
        adn[i * 4 + hh] = d;
    }
}

// ---------------- fused score + softmax (layers 0/1): one wave per node ----------------
__global__ __launch_bounds__(256) void node_softmax01(const int* __restrict__ rowptr,
                                                      const int* __restrict__ csrs,
                                                      const float* __restrict__ asn,
                                                      const float* __restrict__ adn,
                                                      float* __restrict__ sc,
                                                      float* __restrict__ rden) {
    int wid = threadIdx.x >> 6, lane = threadIdx.x & 63;
    int i = blockIdx.x * 4 + wid;
    if (i >= NN) return;
    int start = rowptr[i], end = rowptr[i + 1];
    f32x4 ad = *(const f32x4*)(adn + (size_t)i * 4);
    f32x4 m = {-1e30f, -1e30f, -1e30f, -1e30f};
    for (int e = start + lane; e < end; e += 64) {
        int s = csrs[e];
        f32x4 a = *(const f32x4*)(asn + (size_t)s * 4);
#pragma unroll
        for (int j = 0; j < 4; j++) {
            a[j] = lrelu(a[j] + ad[j]);
            m[j] = fmaxf(m[j], a[j]);
        }
        *(f32x4*)(sc + (size_t)e * 4) = a;
    }
#pragma unroll
    for (int off = 32; off; off >>= 1) {
#pragma unroll
        for (int j = 0; j < 4; j++) m[j] = fmaxf(m[j], __shfl_xor(m[j], off));
    }
    f32x4 den = {0.f, 0.f, 0.f, 0.f};
    for (int e = start + lane; e < end; e += 64) {
        f32x4 s = *(const f32x4*)(sc + (size_t)e * 4);
#pragma unroll
        for (int j = 0; j < 4; j++) s[j] = __expf(s[j] - m[j]);
        *(f32x4*)(sc + (size_t)e * 4) = s;
        den += s;
    }
#pragma unroll
    for (int off = 32; off; off >>= 1) {
#pragma unroll
        for (int j = 0; j < 4; j++) den[j] += __shfl_xor(den[j], off);
    }
    if (lane == 0) {
        f32x4 r;
#pragma unroll
        for (int j = 0; j < 4; j++) r[j] = 1.f / (den[j] + 1e-16f);
        *(f32x4*)(rden + (size_t)i * 4) = r;
    }
}

// ---------------- aggregation + bias + BN + ELU (layers 0/1) ----------------
__global__ __launch_bounds__(128) void agg01(const _Float16* __restrict__ h,
                                             const float* __restrict__ wb,
                                             const float* __restrict__ rden,
                                             const int* __restrict__ rowptr,
                                             const int* __restrict__ csr,
                                             const float* __restrict__ bias,
                                             const float* __restrict__ g,
                                             const float* __restrict__ bt,
                                             const float* __restrict__ mean,
                                             const float* __restrict__ var,
                                             _Float16* __restrict__ out) {
    int i = blockIdx.x;
    int t = threadIdx.x;          // 0..127
    int head = t >> 5;            // 32 threads per head
    int ch = t * 4;               // 4 channels per thread
    int start = rowptr[i], end = rowptr[i + 1];
    f32x4 acc0 = {0.f, 0.f, 0.f, 0.f}, acc1 = {0.f, 0.f, 0.f, 0.f};
    int e = start;
    for (; e + 2 <= end; e += 2) {
        int s0 = csr[e], s1 = csr[e + 1];
        float w0 = wb[(size_t)e * 4 + head];
        float w1 = wb[(size_t)(e + 1) * 4 + head];
        f16x4 p0 = *(const f16x4*)(h + (size_t)s0 * 512 + ch);
        f16x4 p1 = *(const f16x4*)(h + (size_t)s1 * 512 + ch);
#pragma unroll
        for (int j = 0; j < 4; j++) {
            acc0[j] += w0 * (float)p0[j];
            acc1[j] += w1 * (float)p1[j];
        }
    }
    if (e < end) {
        int s0 = csr[e];
        float w0 = wb[(size_t)e * 4 + head];
        f16x4 p0 = *(const f16x4*)(h + (size_t)s0 * 512 + ch);
#pragma unroll
        for (int j = 0; j < 4; j++) acc0[j] += w0 * (float)p0[j];
    }
    float r = rden[i * 4 + head];
    f32x4 bi = *(const f32x4*)(bias + ch);
    f32x4 gg = *(const f32x4*)(g + ch);
    f32x4 bb = *(const f32x4*)(bt + ch);
    f32x4 mm = *(const f32x4*)(mean + ch);
    f32x4 vv = *(const f32x4*)(var + ch);
    f16x4 o;
#pragma unroll
    for (int j = 0; j < 4; j++) {
        float val = (acc0[j] + acc1[j]) * r + bi[j];
        val = (val - mm[j]) * (gg[j] * rsqrtf(vv[j] + BN_EPS)) + bb[j];
        val = val > 0.f ? val : expm1f(val);
        o[j] = (_Float16)val;
    }
    *(f16x4*)(out + (size_t)i * 512 + ch) = o;
}

// ---------------- layer 2 ----------------
__global__ __launch_bounds__(256) void alpha2k(const _Float16* __restrict__ h2,
                                               const float* __restrict__ aws,
                                               const float* __restrict__ awd,
                                               float* __restrict__ asn, float* __restrict__ adn) {
    int wid = threadIdx.x >> 6, lane = threadIdx.x & 63;
    int i = blockIdx.x * 4 + wid;
    if (i >= NN) return;
    const _Float16* row = h2 + (size_t)i * 240;
#pragma unroll
    for (int hh = 0; hh < 6; hh++) {
        float s = 0.f, d = 0.f;
        if (lane < 40) {
            float f = (float)row[hh * 40 + lane];
            s = f * aws[hh * 40 + lane];
            d = f * awd[hh * 40 + lane];
        }
#pragma unroll
        for (int off = 32; off; off >>= 1) {
            s += __shfl_xor(s, off);
            d += __shfl_xor(d, off);
        }
        if (lane == 0) {
            asn[i * 6 + hh] = s;
            adn[i * 6 + hh] = d;
        }
    }
}

__global__ __launch_bounds__(256) void node_softmax2(const int* __restrict__ rowptr,
                                                     const int* __restrict__ csrs,
                                                     const float* __restrict__ asn,
                                                     const float* __restrict__ adn,
                                                     float* __restrict__ sc2,
                                                     float* __restrict__ rden2) {
    int wid = threadIdx.x >> 6, lane = threadIdx.x & 63;
    int i = blockIdx.x * 4 + wid;
    if (i >= NN) return;
    int start = rowptr[i], end = rowptr[i + 1];
    float ad[6], m[6], den[6];
#pragma unroll
    for (int hh = 0; hh < 6; hh++) {
        ad[hh] = adn[i * 6 + hh];
        m[hh] = -1e30f;
        den[hh] = 0.f;
    }
    for (int e = start + lane; e < end; e += 64) {
        int s = csrs[e];
#pragma unroll
        for (int hh = 0; hh < 6; hh++) {
            float v = lrelu(asn[s * 6 + hh] + ad[hh]);
            sc2[(size_t)hh * EPQ + e] = v;
            m[hh] = fmaxf(m[hh], v);
        }
    }
#pragma unroll
    for (int off = 32; off; off >>= 1)
#pragma unroll
        for (int hh = 0; hh < 6; hh++) m[hh] = fmaxf(m[hh], __shfl_xor(m[hh], off));
    for (int e = start + lane; e < end; e += 64) {
#pragma unroll
        for (int hh = 0; hh < 6; hh++) {
            float w = __expf(sc2[(size_t)hh * EPQ + e] - m[hh]);
            sc2[(size_t)hh * EPQ + e] = w;
            den[hh] += w;
        }
    }
#pragma unroll
    for (int off = 32; off; off >>= 1)
#pragma unroll
        for (int hh = 0; hh < 6; hh++) den[hh] += __shfl_xor(den[hh], off);
    if (lane == 0) {
#pragma unroll
        for (int hh = 0; hh < 6; hh++) rden2[i * 6 + hh] = 1.f / (den[hh] + 1e-16f);
    }
}

// ---------------- layer-2 aggregation + head-mean + bias + log_softmax ----------------
__global__ __launch_bounds__(128) void agg2f(const _Float16* __restrict__ h2,
                                             const float* __restrict__ wb2,
                                             const float* __restrict__ rden2,
                                             const int* __restrict__ rowptr,
                                             const int* __restrict__ csr,
                                             const float* __restrict__ b2,
                                             float* __restrict__ out) {
    __shared__ float sval[240];
    int i = blockIdx.x;
    int t = threadIdx.x;
    int start = rowptr[i], end = rowptr[i + 1];
    if (t < 120) {
        int head = t / 20;
        int ch = t * 2;
        const float* wp = wb2 + (size_t)head * EPQ;
        float a0 = 0.f, a1 = 0.f, c0 = 0.f, c1 = 0.f;
        int e = start;
        for (; e + 2 <= end; e += 2) {
            int s0 = csr[e], s1 = csr[e + 1];
            float w0 = wp[e], w1 = wp[e + 1];
            f16x2 p0 = *(const f16x2*)(h2 + (size_t)s0 * 240 + ch);
            f16x2 p1 = *(const f16x2*)(h2 + (size_t)s1 * 240 + ch);
            a0 += w0 * (float)p0[0];
            a1 += w0 * (float)p0[1];
            c0 += w1 * (float)p1[0];
            c1 += w1 * (float)p1[1];
        }
        if (e < end) {
            int s0 = csr[e];
            float w0 = wp[e];
            f16x2 p0 = *(const f16x2*)(h2 + (size_t)s0 * 240 + ch);
            a0 += w0 * (float)p0[0];
            a1 += w0 * (float)p0[1];
        }
        float r = rden2[i * 6 + head];
        sval[ch] = (a0 + c0) * r;
        sval[ch + 1] = (a1 + c1) * r;
    }
    __syncthreads();
    if (t < 64) {
        float v = -INFINITY;
        if (t < 40) {
            float s = 0.f;
#pragma unroll
            for (int hh = 0; hh < 6; hh++) s += sval[hh * 40 + t];
            v = s * (1.0f / 6.0f) + b2[t];
        }
        float mm = v;
#pragma unroll
        for (int off = 32; off; off >>= 1) mm = fmaxf(mm, __shfl_xor(mm, off));
        float se = (t < 40) ? __expf(v - mm) : 0.f;
#pragma unroll
        for (int off = 32; off; off >>= 1) se += __shfl_xor(se, off);
        if (t < 40) out[(size_t)i * 40 + t] = v - mm - logf(se);
    }
}

extern "C" void kernel_launch(void* const* d_in, const int* in_sizes, int n_in,
                              void* d_out, int out_size, void* d_ws, size_t ws_size,
                              hipStream_t stream) {
    const float* x   = (const float*)d_in[0];
    const int*   ei  = (const int*)d_in[1];
    const float* W0  = (const float*)d_in[2];
    const float* as0 = (const float*)d_in[3];
    const float* ad0 = (const float*)d_in[4];
    const float* b0  = (const float*)d_in[5];
    const float* g0  = (const float*)d_in[6];
    const float* bt0 = (const float*)d_in[7];
    const float* m0  = (const float*)d_in[8];
    const float* v0  = (const float*)d_in[9];
    const float* W1  = (const float*)d_in[10];
    const float* as1 = (const float*)d_in[11];
    const float* ad1 = (const float*)d_in[12];
    const float* b1  = (const float*)d_in[13];
    const float* g1  = (const float*)d_in[14];
    const float* bt1 = (const float*)d_in[15];
    const float* m1  = (const float*)d_in[16];
    const float* v1  = (const float*)d_in[17];
    const float* W2  = (const float*)d_in[18];
    const float* as2w = (const float*)d_in[19];
    const float* ad2w = (const float*)d_in[20];
    const float* b2  = (const float*)d_in[21];
    float* out = (float*)d_out;
    const int* srcv = ei;
    const int* dstv = ei + EE;

    char* w = (char*)d_ws;
    auto carve = [&](size_t bytes) {
        char* p = w;
        w += (bytes + 255) & ~(size_t)255;
        return p;
    };
    _Float16* xh   = (_Float16*)carve((size_t)NN * 128 * 2);
    _Float16* hA   = (_Float16*)carve((size_t)NN * 512 * 2);
    _Float16* actB = (_Float16*)carve((size_t)NN * 512 * 2);
    _Float16* W0t  = (_Float16*)carve((size_t)512 * 128 * 2);
    _Float16* W1t  = (_Float16*)carve((size_t)512 * 512 * 2);
    _Float16* W2t  = (_Float16*)carve((size_t)240 * 512 * 2);
    float* asn  = (float*)carve((size_t)NN * 6 * 4);
    float* adn  = (float*)carve((size_t)NN * 6 * 4);
    float* rden = (float*)carve((size_t)NN * 6 * 4);
    float* sc   = (float*)carve((size_t)EPQ * 6 * 4);
    int* count  = (int*)carve((size_t)(NN + 8) * 4);
    int* excl   = (int*)carve((size_t)(NN + 8) * 4);
    int* bsum   = (int*)carve((size_t)512 * 4);
    int* boff   = (int*)carve((size_t)512 * 4);
    int* rowptr = (int*)carve((size_t)(NN + 8) * 4);
    int* cursor = (int*)carve((size_t)(NN + 8) * 4);
    int* csrs   = (int*)carve((size_t)EPQ * 4);
    _Float16* h2 = hA;  // reuse: L2 GEMM output [NN][240]

    // CSR build
    init_count<<<(NN + 255) / 256, 256, 0, stream>>>(count);
    hist_kernel<<<(EE + 255) / 256, 256, 0, stream>>>(dstv, count);
    scan1<<<NBLK, SCB, 0, stream>>>(count, excl, bsum);
    scan2<<<1, 256, 0, stream>>>(bsum, boff);
    scan3<<<(NN + 256) / 256, 256, 0, stream>>>(excl, boff, rowptr, cursor);
    scatter_kernel<<<(EPQ + 255) / 256, 256, 0, stream>>>(srcv, dstv, cursor, csrs);

    // casts
    cast_x_kernel<<<(NN * 128 / 4 + 255) / 256, 256, 0, stream>>>(x, xh, NN * 128 / 4);
    tcast_kernel<<<dim3(16, 4), 256, 0, stream>>>(W0, W0t, 128, 512);
    tcast_kernel<<<dim3(16, 16), 256, 0, stream>>>(W1, W1t, 512, 512);
    tcast_kernel<<<dim3(8, 16), 256, 0, stream>>>(W2, W2t, 512, 240);

    const int MT = (NN + 127) / 128;  // 391

    // Layer 0
    gemm_f16<<<dim3(MT, 4), 256, 0, stream>>>(xh, W0t, hA, NN, 512, 128);
    alpha01<<<(NN + 3) / 4, 256, 0, stream>>>(hA, as0, ad0, asn, adn);
    node_softmax01<<<(NN + 3) / 4, 256, 0, stream>>>(rowptr, csrs, asn, adn, sc, rden);
    agg01<<<NN, 128, 0, stream>>>(hA, sc, rden, rowptr, csrs, b0, g0, bt0, m0, v0, actB);

    // Layer 1
    gemm_f16<<<dim3(MT, 4), 256, 0, stream>>>(actB, W1t, hA, NN, 512, 512);
    alpha01<<<(NN + 3) / 4, 256, 0, stream>>>(hA, as1, ad1, asn, adn);
    node_softmax01<<<(NN + 3) / 4, 256, 0, stream>>>(rowptr, csrs, asn, adn, sc, rden);
    agg01<<<NN, 128, 0, stream>>>(hA, sc, rden, rowptr, csrs, b1, g1, bt1, m1, v1, actB);

    // Layer 2
    gemm_f16<<<dim3(MT, 2), 256, 0, stream>>>(actB, W2t, h2, NN, 240, 512);
    alpha2k<<<(NN + 3) / 4, 256, 0, stream>>>(h2, as2w, ad2w, asn, adn);
    node_softmax2<<<(NN + 3) / 4, 256, 0, stream>>>(rowptr, csrs, asn, adn, sc, rden);
    agg2f<<<NN, 128, 0, stream>>>(h2, sc, rden, rowptr, csrs, b2, out);
}

// Round 4
// 664.436 us; speedup vs baseline: 3.4270x; 1.0716x over previous
//
#include <hip/hip_runtime.h>
#include <cstdint>
#include <cstddef>

#define NN 50000
#define EE 800000
#define EPQ (EE + NN)
#define NEG_SLOPE 0.2f
#define BN_EPS 1e-5f
#define SCB 256
#define NBLK ((NN + SCB - 1) / SCB)
#define MAXD 512

typedef _Float16 f16x8 __attribute__((ext_vector_type(8)));
typedef _Float16 f16x4 __attribute__((ext_vector_type(4)));
typedef _Float16 f16x2 __attribute__((ext_vector_type(2)));
typedef float f32x4 __attribute__((ext_vector_type(4)));
typedef unsigned int u32;

static __device__ __forceinline__ float lrelu(float x) { return x > 0.f ? x : x * NEG_SLOPE; }

// async global->LDS, 16B per lane; LDS dest = wave-uniform base + lane*16
static __device__ __forceinline__ void gld_lds16(const void* g, void* l) {
    __builtin_amdgcn_global_load_lds((const __attribute__((address_space(1))) u32*)g,
                                     (__attribute__((address_space(3))) u32*)l, 16, 0, 0);
}

// ---------------- CSR build ----------------
__global__ void init_count(int* __restrict__ count) {
    int i = blockIdx.x * blockDim.x + threadIdx.x;
    if (i < NN) count[i] = 1;  // self loop
}

__global__ void hist_kernel(const int* __restrict__ dst, int* __restrict__ count) {
    int e = blockIdx.x * blockDim.x + threadIdx.x;
    if (e < EE) atomicAdd(&count[dst[e]], 1);
}

__global__ __launch_bounds__(SCB) void scan1(const int* __restrict__ count,
                                             int* __restrict__ excl, int* __restrict__ bsum) {
    __shared__ int tmp[SCB];
    int b = blockIdx.x, t = threadIdx.x;
    int i = b * SCB + t;
    int v = (i < NN) ? count[i] : 0;
    tmp[t] = v;
    __syncthreads();
    for (int off = 1; off < SCB; off <<= 1) {
        int u = (t >= off) ? tmp[t - off] : 0;
        __syncthreads();
        tmp[t] += u;
        __syncthreads();
    }
    if (i < NN) excl[i] = tmp[t] - v;
    if (t == SCB - 1) bsum[b] = tmp[t];
}

__global__ __launch_bounds__(256) void scan2(const int* __restrict__ bsum, int* __restrict__ boff) {
    __shared__ int tmp[256];
    int t = threadIdx.x;
    int v = (t < NBLK) ? bsum[t] : 0;
    tmp[t] = v;
    __syncthreads();
    for (int off = 1; off < 256; off <<= 1) {
        int u = (t >= off) ? tmp[t - off] : 0;
        __syncthreads();
        tmp[t] += u;
        __syncthreads();
    }
    boff[t] = tmp[t] - v;
}

__global__ void scan3(const int* __restrict__ excl, const int* __restrict__ boff,
                      int* __restrict__ rowptr, int* __restrict__ cursor) {
    int i = blockIdx.x * blockDim.x + threadIdx.x;
    if (i < NN) {
        int r = excl[i] + boff[i / SCB];
        rowptr[i] = r;
        cursor[i] = r;
    }
    if (i == NN) rowptr[NN] = EPQ;
}

__global__ void scatter_kernel(const int* __restrict__ src, const int* __restrict__ dst,
                               int* __restrict__ cursor, int* __restrict__ csrs) {
    int e = blockIdx.x * blockDim.x + threadIdx.x;
    if (e < EE) {
        int d = dst[e];
        int slot = atomicAdd(&cursor[d], 1);
        csrs[slot] = src[e];
    } else if (e < EPQ) {
        int i = e - EE;
        int slot = atomicAdd(&cursor[i], 1);
        csrs[slot] = i;
    }
}

// ---------------- casts ----------------
__global__ void cast_x_kernel(const float* __restrict__ in, _Float16* __restrict__ out, int n4) {
    int i = blockIdx.x * blockDim.x + threadIdx.x;
    if (i >= n4) return;
    f32x4 v = *(const f32x4*)(in + (size_t)i * 4);
    f16x4 o;
    o[0] = (_Float16)v[0]; o[1] = (_Float16)v[1]; o[2] = (_Float16)v[2]; o[3] = (_Float16)v[3];
    *(f16x4*)(out + (size_t)i * 4) = o;
}

// W [K][Nc] f32 -> Wt [Nc][K] f16
__global__ __launch_bounds__(256) void tcast_kernel(const float* __restrict__ W,
                                                    _Float16* __restrict__ Wt, int K, int Nc) {
    __shared__ float tile[32][33];
    int bx = blockIdx.x * 32;
    int by = blockIdx.y * 32;
    int tx = threadIdx.x & 31, ty = threadIdx.x >> 5;
#pragma unroll
    for (int r = 0; r < 32; r += 8) {
        int k = by + ty + r, n = bx + tx;
        tile[ty + r][tx] = (k < K && n < Nc) ? W[(size_t)k * Nc + n] : 0.f;
    }
    __syncthreads();
#pragma unroll
    for (int r = 0; r < 32; r += 8) {
        int n = bx + ty + r, k = by + tx;
        if (n < Nc && k < K) Wt[(size_t)n * K + k] = (_Float16)tile[tx][ty + r];
    }
}

// ---------------- f16 MFMA GEMM, double-buffered 2-phase prefetch ----------------
__global__ __launch_bounds__(256) void gemm_f16(const _Float16* __restrict__ A,
                                                const _Float16* __restrict__ Bt,
                                                _Float16* __restrict__ C, int M, int Nc, int K) {
    __shared__ __align__(16) _Float16 As[2][128 * 64];
    __shared__ __align__(16) _Float16 Bs[2][128 * 64];
    const int t = threadIdx.x;
    const int bm = blockIdx.x * 128;
    const int bn = blockIdx.y * 128;
    const int wid = t >> 6, lane = t & 63;
    const int wm = (wid >> 1) * 64, wn = (wid & 1) * 64;
    f32x4 acc[4][4] = {};
    const int nsteps = K >> 6;

    auto STAGE = [&](int buf, int k0) {
#pragma unroll
        for (int it = 0; it < 4; ++it) {
            int rbase = it * 32 + wid * 8;        // wave-uniform
            int row = rbase + (lane >> 3);
            int c8g = (lane & 7) ^ (row & 7);     // pre-swizzled source chunk
            gld_lds16(A + (size_t)(bm + row) * K + k0 + c8g * 8, (char*)As[buf] + rbase * 128);
            gld_lds16(Bt + (size_t)(bn + row) * K + k0 + c8g * 8, (char*)Bs[buf] + rbase * 128);
        }
    };

    STAGE(0, 0);
    __syncthreads();  // compiler drains vmcnt before barrier -> buf0 ready
    int cur = 0;
    for (int s = 0; s < nsteps; ++s) {
        if (s + 1 < nsteps) STAGE(cur ^ 1, (s + 1) * 64);  // prefetch overlaps compute
#pragma unroll
        for (int ks = 0; ks < 2; ++ks) {
            f16x8 af[4], bf[4];
#pragma unroll
            for (int mi = 0; mi < 4; ++mi) {
                int row = wm + mi * 16 + (lane & 15);
                int c8 = (ks * 4 + (lane >> 4)) ^ (row & 7);
                af[mi] = *(const f16x8*)((const char*)As[cur] + row * 128 + c8 * 16);
            }
#pragma unroll
            for (int ni = 0; ni < 4; ++ni) {
                int row = wn + ni * 16 + (lane & 15);
                int c8 = (ks * 4 + (lane >> 4)) ^ (row & 7);
                bf[ni] = *(const f16x8*)((const char*)Bs[cur] + row * 128 + c8 * 16);
            }
#pragma unroll
            for (int mi = 0; mi < 4; ++mi)
#pragma unroll
                for (int ni = 0; ni < 4; ++ni)
                    acc[mi][ni] = __builtin_amdgcn_mfma_f32_16x16x32_f16(af[mi], bf[ni],
                                                                         acc[mi][ni], 0, 0, 0);
        }
        __syncthreads();  // drains prefetch vmcnt + orders LDS reuse
        cur ^= 1;
    }
#pragma unroll
    for (int mi = 0; mi < 4; ++mi) {
#pragma unroll
        for (int r = 0; r < 4; ++r) {
            int grow = bm + wm + mi * 16 + (lane >> 4) * 4 + r;
            if (grow < M) {
#pragma unroll
                for (int ni = 0; ni < 4; ++ni) {
                    int gcol = bn + wn + ni * 16 + (lane & 15);
                    if (gcol < Nc) C[(size_t)grow * Nc + gcol] = (_Float16)acc[mi][ni][r];
                }
            }
        }
    }
}

// ---------------- alpha (layers 0/1): one wave per node ----------------
__global__ __launch_bounds__(256) void alpha01(const _Float16* __restrict__ h,
                                               const float* __restrict__ aws,
                                               const float* __restrict__ awd,
                                               float* __restrict__ asn, float* __restrict__ adn) {
    int wid = threadIdx.x >> 6, lane = threadIdx.x & 63;
    int i = blockIdx.x * 4 + wid;
    if (i >= NN) return;
    f16x8 v = *(const f16x8*)(h + (size_t)i * 512 + lane * 8);
    float s = 0.f, d = 0.f;
#pragma unroll
    for (int j = 0; j < 8; j++) {
        float f = (float)v[j];
        s += f * aws[lane * 8 + j];
        d += f * awd[lane * 8 + j];
    }
#pragma unroll
    for (int off = 1; off < 16; off <<= 1) {
        s += __shfl_xor(s, off);
        d += __shfl_xor(d, off);
    }
    if ((lane & 15) == 0) {
        int hh = lane >> 4;
        asn[i * 4 + hh] = s;
        adn[i * 4 + hh] = d;
    }
}

// ---------------- fused softmax + aggregation + bias + BN + ELU (layers 0/1) ----------------
__global__ __launch_bounds__(128) void agg01(const _Float16* __restrict__ h,
                                             const float* __restrict__ asn,
                                             const float* __restrict__ adn,
                                             const int* __restrict__ rowptr,
                                             const int* __restrict__ csr,
                                             const float* __restrict__ bias,
                                             const float* __restrict__ g,
                                             const float* __restrict__ bt,
                                             const float* __restrict__ mean,
                                             const float* __restrict__ var,
                                             _Float16* __restrict__ out) {
    __shared__ __align__(16) float ws[MAXD][4];
    __shared__ u32 soff[MAXD];
    __shared__ float srden[4], smx[4];
    int i = blockIdx.x;
    int t = threadIdx.x;  // 128
    int start = rowptr[i], end = rowptr[i + 1];
    int deg = end - start;
    bool fits = deg <= MAXD;
    f32x4 ad = *(const f32x4*)(adn + (size_t)i * 4);
    // phase 1a: scores + src byte-offsets into LDS
    if (fits) {
        for (int e = t; e < deg; e += 128) {
            int s = csr[start + e];
            soff[e] = (u32)s * 1024u;  // 512 ch * 2B
            f32x4 a = *(const f32x4*)(asn + (size_t)s * 4);
#pragma unroll
            for (int j = 0; j < 4; j++) a[j] = lrelu(a[j] + ad[j]);
            *(f32x4*)ws[e] = a;
        }
    }
    __syncthreads();
    int head = t >> 5, lane32 = t & 31;
    // phase 1b: per-head max & denom (32 lanes per head; xor<32 stays in group)
    {
        float m = -1e30f, den = 0.f;
        if (fits) {
            for (int e = lane32; e < deg; e += 32) m = fmaxf(m, ws[e][head]);
        } else {
            for (int e = start + lane32; e < end; e += 32)
                m = fmaxf(m, lrelu(asn[(size_t)csr[e] * 4 + head] + ad[head]));
        }
#pragma unroll
        for (int off = 16; off; off >>= 1) m = fmaxf(m, __shfl_xor(m, off));
        if (fits) {
            for (int e = lane32; e < deg; e += 32) {
                float w = __expf(ws[e][head] - m);
                ws[e][head] = w;
                den += w;
            }
        } else {
            for (int e = start + lane32; e < end; e += 32)
                den += __expf(lrelu(asn[(size_t)csr[e] * 4 + head] + ad[head]) - m);
        }
#pragma unroll
        for (int off = 16; off; off >>= 1) den += __shfl_xor(den, off);
        if (lane32 == 0) {
            srden[head] = 1.f / (den + 1e-16f);
            smx[head] = m;
        }
    }
    __syncthreads();
    // phase 2: aggregation, 4-edge unroll, u32 offsets
    int ch = t * 4;  // head = t>>5 consistent with ch/128
    const char* hb = (const char*)h + (size_t)ch * 2;
    f32x4 a0 = {0, 0, 0, 0}, a1 = {0, 0, 0, 0}, a2 = {0, 0, 0, 0}, a3 = {0, 0, 0, 0};
    if (fits) {
        int e = 0;
        for (; e + 4 <= deg; e += 4) {
            u32 o0 = soff[e], o1 = soff[e + 1], o2 = soff[e + 2], o3 = soff[e + 3];
            float w0 = ws[e][head], w1 = ws[e + 1][head];
            float w2 = ws[e + 2][head], w3 = ws[e + 3][head];
            f16x4 p0 = *(const f16x4*)(hb + o0);
            f16x4 p1 = *(const f16x4*)(hb + o1);
            f16x4 p2 = *(const f16x4*)(hb + o2);
            f16x4 p3 = *(const f16x4*)(hb + o3);
#pragma unroll
            for (int j = 0; j < 4; j++) {
                a0[j] += w0 * (float)p0[j];
                a1[j] += w1 * (float)p1[j];
                a2[j] += w2 * (float)p2[j];
                a3[j] += w3 * (float)p3[j];
            }
        }
        for (; e < deg; e++) {
            float w0 = ws[e][head];
            f16x4 p0 = *(const f16x4*)(hb + soff[e]);
#pragma unroll
            for (int j = 0; j < 4; j++) a0[j] += w0 * (float)p0[j];
        }
    } else {
        float m = smx[head];
        for (int e = start; e < end; e++) {
            int s = csr[e];
            float w0 = __expf(lrelu(asn[(size_t)s * 4 + head] + ad[head]) - m);
            f16x4 p0 = *(const f16x4*)(hb + (size_t)s * 1024u);
#pragma unroll
            for (int j = 0; j < 4; j++) a0[j] += w0 * (float)p0[j];
        }
    }
    float r = srden[head];
    f32x4 bi = *(const f32x4*)(bias + ch);
    f32x4 gg = *(const f32x4*)(g + ch);
    f32x4 bb = *(const f32x4*)(bt + ch);
    f32x4 mm = *(const f32x4*)(mean + ch);
    f32x4 vv = *(const f32x4*)(var + ch);
    f16x4 o;
#pragma unroll
    for (int j = 0; j < 4; j++) {
        float val = (a0[j] + a1[j] + a2[j] + a3[j]) * r + bi[j];
        val = (val - mm[j]) * (gg[j] * rsqrtf(vv[j] + BN_EPS)) + bb[j];
        val = val > 0.f ? val : expm1f(val);
        o[j] = (_Float16)val;
    }
    *(f16x4*)(out + (size_t)i * 512 + ch) = o;
}

// ---------------- layer 2: alpha (padded stride 8) ----------------
__global__ __launch_bounds__(256) void alpha2k(const _Float16* __restrict__ h2,
                                               const float* __restrict__ aws,
                                               const float* __restrict__ awd,
                                               float* __restrict__ asn, float* __restrict__ adn) {
    int wid = threadIdx.x >> 6, lane = threadIdx.x & 63;
    int i = blockIdx.x * 4 + wid;
    if (i >= NN) return;
    const _Float16* row = h2 + (size_t)i * 240;
#pragma unroll
    for (int hh = 0; hh < 6; hh++) {
        float s = 0.f, d = 0.f;
        if (lane < 40) {
            float f = (float)row[hh * 40 + lane];
            s = f * aws[hh * 40 + lane];
            d = f * awd[hh * 40 + lane];
        }
#pragma unroll
        for (int off = 32; off; off >>= 1) {
            s += __shfl_xor(s, off);
            d += __shfl_xor(d, off);
        }
        if (lane == 0) {
            asn[(size_t)i * 8 + hh] = s;
            adn[(size_t)i * 8 + hh] = d;
        }
    }
}

// ---------------- fused layer-2 softmax + aggregation + mean + bias + log_softmax ----------------
__global__ __launch_bounds__(192) void agg2f(const _Float16* __restrict__ h2,
                                             const float* __restrict__ asn,
                                             const float* __restrict__ adn,
                                             const int* __restrict__ rowptr,
                                             const int* __restrict__ csr,
                                             const float* __restrict__ b2,
                                             float* __restrict__ out) {
    __shared__ __align__(16) float ws6[MAXD][6];
    __shared__ u32 soff[MAXD];
    __shared__ float srd[6], smx[6];
    __shared__ float sval[240];
    int i = blockIdx.x;
    int t = threadIdx.x;  // 192
    int start = rowptr[i], end = rowptr[i + 1];
    int deg = end - start;
    bool fits = deg <= MAXD;
    f32x4 ad0 = *(const f32x4*)(adn + (size_t)i * 8);
    f32x4 ad1 = *(const f32x4*)(adn + (size_t)i * 8 + 4);
    float adh[6] = {ad0[0], ad0[1], ad0[2], ad0[3], ad1[0], ad1[1]};
    if (fits) {
        for (int e = t; e < deg; e += 192) {
            int s = csr[start + e];
            soff[e] = (u32)s * 480u;  // 240 ch * 2B
            f32x4 x0 = *(const f32x4*)(asn + (size_t)s * 8);
            f32x4 x1 = *(const f32x4*)(asn + (size_t)s * 8 + 4);
            float av[6] = {x0[0], x0[1], x0[2], x0[3], x1[0], x1[1]};
#pragma unroll
            for (int hh = 0; hh < 6; hh++) ws6[e][hh] = lrelu(av[hh] + adh[hh]);
        }
    }
    __syncthreads();
    int head6 = t >> 5, lane32 = t & 31;  // 6 heads x 32 lanes
    {
        float m = -1e30f, den = 0.f;
        if (fits) {
            for (int e = lane32; e < deg; e += 32) m = fmaxf(m, ws6[e][head6]);
        } else {
            for (int e = start + lane32; e < end; e += 32)
                m = fmaxf(m, lrelu(asn[(size_t)csr[e] * 8 + head6] + adh[head6]));
        }
#pragma unroll
        for (int off = 16; off; off >>= 1) m = fmaxf(m, __shfl_xor(m, off));
        if (fits) {
            for (int e = lane32; e < deg; e += 32) {
                float w = __expf(ws6[e][head6] - m);
                ws6[e][head6] = w;
                den += w;
            }
        } else {
            for (int e = start + lane32; e < end; e += 32)
                den += __expf(lrelu(asn[(size_t)csr[e] * 8 + head6] + adh[head6]) - m);
        }
#pragma unroll
        for (int off = 16; off; off >>= 1) den += __shfl_xor(den, off);
        if (lane32 == 0) {
            srd[head6] = 1.f / (den + 1e-16f);
            smx[head6] = m;
        }
    }
    __syncthreads();
    if (t < 120) {
        int head = t / 20;
        int ch = t * 2;
        const char* hb = (const char*)h2 + (size_t)ch * 2;
        float a0 = 0.f, a1 = 0.f, b0 = 0.f, b1 = 0.f;
        if (fits) {
            int e = 0;
            for (; e + 2 <= deg; e += 2) {
                u32 o0 = soff[e], o1 = soff[e + 1];
                float w0 = ws6[e][head], w1 = ws6[e + 1][head];
                f16x2 p0 = *(const f16x2*)(hb + o0);
                f16x2 p1 = *(const f16x2*)(hb + o1);
                a0 += w0 * (float)p0[0];
                a1 += w0 * (float)p0[1];
                b0 += w1 * (float)p1[0];
                b1 += w1 * (float)p1[1];
            }
            if (e < deg) {
                float w0 = ws6[e][head];
                f16x2 p0 = *(const f16x2*)(hb + soff[e]);
                a0 += w0 * (float)p0[0];
                a1 += w0 * (float)p0[1];
            }
        } else {
            float m = smx[head];
            for (int e = start; e < end; e++) {
                int s = csr[e];
                float w0 = __expf(lrelu(asn[(size_t)s * 8 + head] + adh[head]) - m);
                f16x2 p0 = *(const f16x2*)(hb + (size_t)s * 480u);
                a0 += w0 * (float)p0[0];
                a1 += w0 * (float)p0[1];
            }
        }
        float r = srd[head];
        sval[ch] = (a0 + b0) * r;
        sval[ch + 1] = (a1 + b1) * r;
    }
    __syncthreads();
    if (t < 64) {
        float v = -INFINITY;
        if (t < 40) {
            float s = 0.f;
#pragma unroll
            for (int hh = 0; hh < 6; hh++) s += sval[hh * 40 + t];
            v = s * (1.0f / 6.0f) + b2[t];
        }
        float mm = v;
#pragma unroll
        for (int off = 32; off; off >>= 1) mm = fmaxf(mm, __shfl_xor(mm, off));
        float se = (t < 40) ? __expf(v - mm) : 0.f;
#pragma unroll
        for (int off = 32; off; off >>= 1) se += __shfl_xor(se, off);
        if (t < 40) out[(size_t)i * 40 + t] = v - mm - logf(se);
    }
}

extern "C" void kernel_launch(void* const* d_in, const int* in_sizes, int n_in,
                              void* d_out, int out_size, void* d_ws, size_t ws_size,
                              hipStream_t stream) {
    const float* x   = (const float*)d_in[0];
    const int*   ei  = (const int*)d_in[1];
    const float* W0  = (const float*)d_in[2];
    const float* as0 = (const float*)d_in[3];
    const float* ad0 = (const float*)d_in[4];
    const float* b0  = (const float*)d_in[5];
    const float* g0  = (const float*)d_in[6];
    const float* bt0 = (const float*)d_in[7];
    const float* m0  = (const float*)d_in[8];
    const float* v0  = (const float*)d_in[9];
    const float* W1  = (const float*)d_in[10];
    const float* as1 = (const float*)d_in[11];
    const float* ad1 = (const float*)d_in[12];
    const float* b1  = (const float*)d_in[13];
    const float* g1  = (const float*)d_in[14];
    const float* bt1 = (const float*)d_in[15];
    const float* m1  = (const float*)d_in[16];
    const float* v1  = (const float*)d_in[17];
    const float* W2  = (const float*)d_in[18];
    const float* as2w = (const float*)d_in[19];
    const float* ad2w = (const float*)d_in[20];
    const float* b2  = (const float*)d_in[21];
    float* out = (float*)d_out;
    const int* srcv = ei;
    const int* dstv = ei + EE;

    char* w = (char*)d_ws;
    auto carve = [&](size_t bytes) {
        char* p = w;
        w += (bytes + 255) & ~(size_t)255;
        return p;
    };
    _Float16* xh   = (_Float16*)carve((size_t)NN * 128 * 2);
    _Float16* hA   = (_Float16*)carve((size_t)NN * 512 * 2);
    _Float16* actB = (_Float16*)carve((size_t)NN * 512 * 2);
    _Float16* W0t  = (_Float16*)carve((size_t)512 * 128 * 2);
    _Float16* W1t  = (_Float16*)carve((size_t)512 * 512 * 2);
    _Float16* W2t  = (_Float16*)carve((size_t)240 * 512 * 2);
    float* asn  = (float*)carve((size_t)NN * 8 * 4);
    float* adn  = (float*)carve((size_t)NN * 8 * 4);
    int* count  = (int*)carve((size_t)(NN + 8) * 4);
    int* excl   = (int*)carve((size_t)(NN + 8) * 4);
    int* bsum   = (int*)carve((size_t)512 * 4);
    int* boff   = (int*)carve((size_t)512 * 4);
    int* rowptr = (int*)carve((size_t)(NN + 8) * 4);
    int* cursor = (int*)carve((size_t)(NN + 8) * 4);
    int* csrs   = (int*)carve((size_t)EPQ * 4);
    _Float16* h2 = hA;  // reuse: L2 GEMM output [NN][240]

    // CSR build
    init_count<<<(NN + 255) / 256, 256, 0, stream>>>(count);
    hist_kernel<<<(EE + 255) / 256, 256, 0, stream>>>(dstv, count);
    scan1<<<NBLK, SCB, 0, stream>>>(count, excl, bsum);
    scan2<<<1, 256, 0, stream>>>(bsum, boff);
    scan3<<<(NN + 256) / 256, 256, 0, stream>>>(excl, boff, rowptr, cursor);
    scatter_kernel<<<(EPQ + 255) / 256, 256, 0, stream>>>(srcv, dstv, cursor, csrs);

    // casts
    cast_x_kernel<<<(NN * 128 / 4 + 255) / 256, 256, 0, stream>>>(x, xh, NN * 128 / 4);
    tcast_kernel<<<dim3(16, 4), 256, 0, stream>>>(W0, W0t, 128, 512);
    tcast_kernel<<<dim3(16, 16), 256, 0, stream>>>(W1, W1t, 512, 512);
    tcast_kernel<<<dim3(8, 16), 256, 0, stream>>>(W2, W2t, 512, 240);

    const int MT = (NN + 127) / 128;  // 391

    // Layer 0
    gemm_f16<<<dim3(MT, 4), 256, 0, stream>>>(xh, W0t, hA, NN, 512, 128);
    alpha01<<<(NN + 3) / 4, 256, 0, stream>>>(hA, as0, ad0, asn, adn);
    agg01<<<NN, 128, 0, stream>>>(hA, asn, adn, rowptr, csrs, b0, g0, bt0, m0, v0, actB);

    // Layer 1
    gemm_f16<<<dim3(MT, 4), 256, 0, stream>>>(actB, W1t, hA, NN, 512, 512);
    alpha01<<<(NN + 3) / 4, 256, 0, stream>>>(hA, as1, ad1, asn, adn);
    agg01<<<NN, 128, 0, stream>>>(hA, asn, adn, rowptr, csrs, b1, g1, bt1, m1, v1, actB);

    // Layer 2
    gemm_f16<<<dim3(MT, 2), 256, 0, stream>>>(actB, W2t, h2, NN, 240, 512);
    alpha2k<<<(NN + 3) / 4, 256, 0, stream>>>(h2, as2w, ad2w, asn, adn);
    agg2f<<<NN, 192, 0, stream>>>(h2, asn, adn, rowptr, csrs, b2, out);
}